// Round 1
// baseline (5344.050 us; speedup 1.0000x reference)
//
#include <hip/hip_runtime.h>
#include <cstdint>
#include <cstddef>

typedef unsigned short u16;
typedef unsigned int u32;
typedef unsigned long long u64;

typedef short short8 __attribute__((ext_vector_type(8)));
typedef float floatx4 __attribute__((ext_vector_type(4)));

// Problem constants: B=32, T=512, D=256, H=256, 4H=1024, C=32
// Workspace layout (bytes)
#define O_EMB    0ull                 // emb bf16 [16384][256]
#define O_XG     8388608ull           // xg bf16 [2][512][1024][32]  (t, gate*256+dim, batch)
#define O_HS     75497472ull          // hs bf16 [2][16384][256]
#define O_HST    92274688ull          // (unused)
#define O_LOGITS 92340224ull          // logits f32 [16384][32]; ALSO WhT bf16 [2][1024][256] (live k0->k3 only)
#define O_WIT    94437504ull          // WiT bf16 [2][1024][256]
#define O_OUTW   95486080ull          // outW bf16 [512][32]
#define O_FLAGS  95518848ull          // (unused)
#define WS_NEED  95520896ull

__device__ __forceinline__ u16 f2bf(float x) {
    u32 u = __float_as_uint(x);
    u += 0x7fffu + ((u >> 16) & 1u);
    return (u16)(u >> 16);
}
__device__ __forceinline__ float bf2f(u16 v) { return __uint_as_float(((u32)v) << 16); }
__device__ __forceinline__ float sigm(float x) { return 1.0f / (1.0f + __expf(-x)); }
__device__ __forceinline__ float tanh_f(float x) {
    x = fminf(30.0f, fmaxf(-30.0f, x));
    float e = __expf(-2.0f * x);
    return (1.0f - e) / (1.0f + e);
}

// ---------------- K0: Wi/Wh -> transposed bf16 [n][k], out_W -> bf16 ---------------
__global__ __launch_bounds__(256) void k0_prep(const float* __restrict__ Wi_f, const float* __restrict__ Wi_b,
                                               const float* __restrict__ Wh_f, const float* __restrict__ Wh_b,
                                               const float* __restrict__ out_W,
                                               u16* __restrict__ WiT, u16* __restrict__ WhT,
                                               u16* __restrict__ outWb) {
    int id = blockIdx.x * 256 + threadIdx.x;   // grid 4160*256 = 1064960 exact
    if (id < 524288) {
        int d = id >> 18;
        int rem = id & 262143;
        int k = rem >> 10;
        int n = rem & 1023;
        const float* Wi = d ? Wi_b : Wi_f;
        WiT[(size_t)d * 262144 + (size_t)n * 256 + k] = f2bf(Wi[(size_t)k * 1024 + n]);
    } else if (id < 540672) {
        int id2 = id - 524288;                 // < 16384
        outWb[id2] = f2bf(out_W[id2]);
    } else {
        int id2 = id - 540672;                 // < 524288
        int d = id2 >> 18;
        int rem = id2 & 262143;
        int k = rem >> 10;
        int n = rem & 1023;
        const float* Wh = d ? Wh_b : Wh_f;
        WhT[(size_t)d * 262144 + (size_t)n * 256 + k] = f2bf(Wh[(size_t)k * 1024 + n]);
    }
}

// ---------------- K1: embedding gather -> emb bf16 [r=t*32+b][256] -----------------
__global__ __launch_bounds__(256) void k1_embed(const int* __restrict__ chars, const int* __restrict__ bigrams,
                                                const float* __restrict__ ct, const float* __restrict__ bt,
                                                u16* __restrict__ emb) {
    int idx = blockIdx.x * 256 + threadIdx.x;  // grid 8192*256 = 2097152 = 16384*128
    int r = idx >> 7;
    int p2 = (idx & 127) << 1;
    int t = r >> 5, b = r & 31;
    const float* src;
    if (p2 < 128) src = ct + (size_t)chars[b * 512 + t] * 128 + p2;
    else          src = bt + (size_t)bigrams[b * 512 + t] * 128 + (p2 - 128);
    float2 v = *(const float2*)(const void*)src;
    u32 pk = (u32)f2bf(v.x) | ((u32)f2bf(v.y) << 16);
    *(u32*)(void*)(emb + (size_t)r * 256 + p2) = pk;
}

// ---------------- K2: xg[d][t][n][b] = emb @ Wi_d + b_d  (bf16 MFMA) ---------------
// Store layout changed to [t][1024][32] so k3 reads 4 batches per u64.
__global__ __launch_bounds__(256) void k2_gemm(const u16* __restrict__ emb, const u16* __restrict__ WiT,
                                               const float* __restrict__ b_f, const float* __restrict__ b_b,
                                               u16* __restrict__ xg) {
    int mbase = blockIdx.x * 64;
    int nbase = blockIdx.y * 64;
    int d = blockIdx.z;
    const u16* Bt = WiT + (size_t)d * 262144;
    const float* bias = d ? b_b : b_f;
    u16* xgd = xg + (size_t)d * 16777216ull;
    int tid = threadIdx.x;
    int wv = tid >> 6, l = tid & 63, lm = l & 15, lq = l >> 4;
    floatx4 acc[4] = {{0,0,0,0},{0,0,0,0},{0,0,0,0},{0,0,0,0}};
    int arow = mbase + wv * 16 + lm;
#pragma unroll
    for (int kc = 0; kc < 8; ++kc) {
        int k0 = kc * 32 + lq * 8;
        short8 a = *(const short8*)(const void*)(emb + (size_t)arow * 256 + k0);
#pragma unroll
        for (int nt = 0; nt < 4; ++nt) {
            short8 bb = *(const short8*)(const void*)(Bt + (size_t)(nbase + nt * 16 + lm) * 256 + k0);
            acc[nt] = __builtin_amdgcn_mfma_f32_16x16x32_bf16(a, bb, acc[nt], 0, 0, 0);
        }
    }
    // rows rr0..rr0+3 lie in one 32-row (one t) block since mbase is 64-aligned
    int rr0 = mbase + wv * 16 + lq * 4;
    int tt = rr0 >> 5, b0 = rr0 & 31;
#pragma unroll
    for (int nt = 0; nt < 4; ++nt) {
        int n = nbase + nt * 16 + lm;
        float bv = bias[n];
        u64 pk = (u64)f2bf(acc[nt][0] + bv)
               | ((u64)f2bf(acc[nt][1] + bv) << 16)
               | ((u64)f2bf(acc[nt][2] + bv) << 32)
               | ((u64)f2bf(acc[nt][3] + bv) << 48);
        *(u64*)(void*)(xgd + ((size_t)tt * 1024 + n) * 32 + b0) = pk;
    }
}

// ---------------- K3: BiLSTM recurrence, batch-split (NO inter-block sync) ---------
// 4 blocks: (dir = bid>>1, half = bid&1). Each block: 1024 threads = 16 waves,
// owns 16 batches and the FULL H=256. Wh lives in VGPRs as pre-laid MFMA B-frags
// (128 VGPR/thread). Wave w owns gate columns {w,w+16,w+32,w+48}*16 -> each thread
// holds i/f/g/o for (dim c, 4 batches): elementwise is register-local, c-state in
// VGPRs. h exchanged via double-buffered LDS; one s_barrier + lgkmcnt(0) per step
// (hs history stores intentionally left in flight across the barrier).
__global__ __launch_bounds__(1024) void k3_lstm(const u16* __restrict__ xg, const u16* __restrict__ WhT,
                                                const int* __restrict__ seq_len, u16* __restrict__ hs) {
    int bid = blockIdx.x;
    int dir = bid >> 1;
    int half = bid & 1;
    const u16* xgd = xg + (size_t)dir * 16777216ull;
    const u16* whd = WhT + (size_t)dir * 262144ull;
    u16* hsd = hs + (size_t)dir * 4194304ull;

    // 84.5 KB static LDS: guarantees 1 block/CU (MFMA pipe not shared).
    // Buffers: [16 batches][pitch 264 bf16] -> 8-slot spread on b128 A-frag reads.
    __shared__ __align__(16) u16 h_all[2][21120];

    int tid = threadIdx.x;
    int wv = tid >> 6;
    int l = tid & 63;
    int lm = l & 15, lq = l >> 4;
    int c_dim = wv * 16 + lm;

    // Wh B-fragments: whb[g][kc] covers gate col n = g*256 + c_dim, k = kc*32+lq*8..+8
    short8 whb[4][8];
#pragma unroll
    for (int g = 0; g < 4; ++g)
#pragma unroll
        for (int kc = 0; kc < 8; ++kc)
            whb[g][kc] = *(const short8*)(const void*)(whd + (size_t)(g * 256 + c_dim) * 256 + kc * 32 + lq * 8);

    float cst[4] = {0.f, 0.f, 0.f, 0.f};
    int Lr[4];
#pragma unroll
    for (int r = 0; r < 4; ++r) Lr[r] = seq_len[half * 16 + lq * 4 + r];

    for (int i = tid; i < 4224; i += 1024) h_all[0][i] = 0;   // h_{-1} = 0
    __syncthreads();

    const int aoff = lm * 264 + lq * 8;   // A-frag: row=batch lm, k=kc*32+lq*8..+8
    const int hrow = lq * 4;

    for (int s = 0; s < 512; ++s) {
        int t = dir ? (511 - s) : s;
        // xg for this step: 4 gates x 4 batches, u64 each (consumed ~2.5k cyc later)
        const u16* xbase = xgd + (size_t)t * 32768 + (size_t)c_dim * 32 + half * 16 + lq * 4;
        u64 xq0 = *(const u64*)(const void*)(xbase);
        u64 xq1 = *(const u64*)(const void*)(xbase + 8192);
        u64 xq2 = *(const u64*)(const void*)(xbase + 16384);
        u64 xq3 = *(const u64*)(const void*)(xbase + 24576);

        const u16* hb = h_all[s & 1];
        floatx4 acc0 = {0,0,0,0}, acc1 = {0,0,0,0}, acc2 = {0,0,0,0}, acc3 = {0,0,0,0};
#pragma unroll
        for (int kc = 0; kc < 8; ++kc) {
            short8 a = *(const short8*)(const void*)(hb + aoff + kc * 32);
            acc0 = __builtin_amdgcn_mfma_f32_16x16x32_bf16(a, whb[0][kc], acc0, 0, 0, 0);
            acc1 = __builtin_amdgcn_mfma_f32_16x16x32_bf16(a, whb[1][kc], acc1, 0, 0, 0);
            acc2 = __builtin_amdgcn_mfma_f32_16x16x32_bf16(a, whb[2][kc], acc2, 0, 0, 0);
            acc3 = __builtin_amdgcn_mfma_f32_16x16x32_bf16(a, whb[3][kc], acc3, 0, 0, 0);
        }

        u16* hw = h_all[(s & 1) ^ 1];
#pragma unroll
        for (int r = 0; r < 4; ++r) {
            float gi = acc0[r] + bf2f((u16)(xq0 >> (16 * r)));
            float gf = acc1[r] + bf2f((u16)(xq1 >> (16 * r)));
            float gg = acc2[r] + bf2f((u16)(xq2 >> (16 * r)));
            float go = acc3[r] + bf2f((u16)(xq3 >> (16 * r)));
            float ig = sigm(gi), fg = sigm(gf), gt = tanh_f(gg), og = sigm(go);
            float cn = fg * cst[r] + ig * gt;
            float hn = og * tanh_f(cn);
            if (dir && t >= Lr[r]) { cn = cst[r]; hn = 0.0f; }   // backward: masked suffix stays 0
            cst[r] = cn;
            u16 hbf = f2bf(hn);
            hw[(hrow + r) * 264 + c_dim] = hbf;                  // h for next step (LDS)
            hsd[((size_t)(t * 32 + half * 16 + hrow + r)) * 256 + c_dim] = hbf;  // history for k4
        }
        // Barrier WITHOUT vmcnt drain: only LDS writes must be visible; global hs
        // stores stay in flight (nothing in-kernel reads them).
        asm volatile("s_waitcnt lgkmcnt(0)" ::: "memory");
        __builtin_amdgcn_sched_barrier(0);
        __builtin_amdgcn_s_barrier();
        __builtin_amdgcn_sched_barrier(0);
    }
}

// ---------------- K4: logits = log_softmax([hf;hb] @ out_W + out_b) ---------------
__global__ __launch_bounds__(256) void k4_proj(const u16* __restrict__ hs, const u16* __restrict__ outWb,
                                               const float* __restrict__ out_b, float* __restrict__ logits) {
    int r = blockIdx.x * 8 + (threadIdx.x >> 5);
    int n = threadIdx.x & 31;
    const u16* hf = hs + (size_t)r * 256;
    const u16* hbk = hs + 4194304ull + (size_t)r * 256;
    float acc = out_b[n];
#pragma unroll 4
    for (int k = 0; k < 256; k += 2) {
        u32 hv = *(const u32*)(const void*)(hf + k);
        acc += bf2f((u16)hv) * bf2f(outWb[k * 32 + n]);
        acc += bf2f((u16)(hv >> 16)) * bf2f(outWb[(k + 1) * 32 + n]);
    }
#pragma unroll 4
    for (int k = 0; k < 256; k += 2) {
        u32 hv = *(const u32*)(const void*)(hbk + k);
        acc += bf2f((u16)hv) * bf2f(outWb[(256 + k) * 32 + n]);
        acc += bf2f((u16)(hv >> 16)) * bf2f(outWb[(257 + k) * 32 + n]);
    }
    float m = acc;
#pragma unroll
    for (int d2 = 16; d2 >= 1; d2 >>= 1) m = fmaxf(m, __shfl_xor(m, d2, 32));
    float s = __expf(acc - m);
#pragma unroll
    for (int d2 = 16; d2 >= 1; d2 >>= 1) s += __shfl_xor(s, d2, 32);
    logits[(size_t)r * 32 + n] = acc - m - __logf(s);
}

// ---------------- K5: CRF forward + gold score -> out[b] --------------------------
__global__ __launch_bounds__(256) void k5_crf(const float* __restrict__ logits, const int* __restrict__ target,
                                              const int* __restrict__ seq_len, const float* __restrict__ trans,
                                              const float* __restrict__ start_trans, const float* __restrict__ end_trans,
                                              float* __restrict__ out) {
    int b = blockIdx.x;
    int tid = threadIdx.x;
    int L = seq_len[b];
    __shared__ float alpha[32];
    __shared__ float red[4];
    __shared__ float goldsh;

    // gold path score
    float part = 0.0f;
    for (int t = tid; t < 512; t += 256) {
        if (t < L) {
            int tg = target[b * 512 + t];
            part += logits[((size_t)(t * 32 + b)) * 32 + tg];
            if (t >= 1) part += trans[target[b * 512 + t - 1] * 32 + tg];
        }
    }
#pragma unroll
    for (int d2 = 32; d2 >= 1; d2 >>= 1) part += __shfl_xor(part, d2, 64);
    if ((tid & 63) == 0) red[tid >> 6] = part;
    __syncthreads();
    if (tid == 0) {
        float g = red[0] + red[1] + red[2] + red[3];
        g += start_trans[target[b * 512]];
        g += end_trans[target[b * 512 + L - 1]];
        goldsh = g;
    }
    if (tid < 32) alpha[tid] = logits[(size_t)b * 32 + tid] + start_trans[tid];
    __syncthreads();

    int j = tid >> 3, uu = tid & 7;
    float tr4[4];
#pragma unroll
    for (int r = 0; r < 4; ++r) tr4[r] = trans[(uu * 4 + r) * 32 + j];
    float e_next = logits[((size_t)(32 + b)) * 32 + j];
    for (int t = 1; t < 512; ++t) {
        float e = e_next;
        if (t < 511) e_next = logits[((size_t)((t + 1) * 32 + b)) * 32 + j];
        float a0 = alpha[uu * 4 + 0] + tr4[0];
        float a1 = alpha[uu * 4 + 1] + tr4[1];
        float a2 = alpha[uu * 4 + 2] + tr4[2];
        float a3 = alpha[uu * 4 + 3] + tr4[3];
        float m = fmaxf(fmaxf(a0, a1), fmaxf(a2, a3));
#pragma unroll
        for (int d2 = 4; d2 >= 1; d2 >>= 1) m = fmaxf(m, __shfl_xor(m, d2, 8));
        float ss = __expf(a0 - m) + __expf(a1 - m) + __expf(a2 - m) + __expf(a3 - m);
#pragma unroll
        for (int d2 = 4; d2 >= 1; d2 >>= 1) ss += __shfl_xor(ss, d2, 8);
        float nv = e + m + __logf(ss);
        __syncthreads();
        if (uu == 0 && t < L) alpha[j] = nv;
        __syncthreads();
    }
    if (tid < 32) {
        float v = alpha[tid] + end_trans[tid];
        float m = v;
#pragma unroll
        for (int d2 = 16; d2 >= 1; d2 >>= 1) m = fmaxf(m, __shfl_xor(m, d2, 32));
        float s2 = __expf(v - m);
#pragma unroll
        for (int d2 = 16; d2 >= 1; d2 >>= 1) s2 += __shfl_xor(s2, d2, 32);
        if (tid == 0) out[b] = m + __logf(s2) - goldsh;
    }
}

extern "C" void kernel_launch(void* const* d_in, const int* in_sizes, int n_in,
                              void* d_out, int out_size, void* d_ws, size_t ws_size,
                              hipStream_t stream) {
    if (ws_size < WS_NEED) return;  // workspace too small: fail cleanly, no OOB
    const int* chars = (const int*)d_in[0];
    const int* bigrams = (const int*)d_in[1];
    const int* seq_len = (const int*)d_in[2];
    const int* target = (const int*)d_in[3];
    const float* char_table = (const float*)d_in[4];
    const float* bigram_table = (const float*)d_in[5];
    const float* Wi_f = (const float*)d_in[6];
    const float* Wh_f = (const float*)d_in[7];
    const float* b_f = (const float*)d_in[8];
    const float* Wi_b = (const float*)d_in[9];
    const float* Wh_b = (const float*)d_in[10];
    const float* b_b = (const float*)d_in[11];
    const float* out_W = (const float*)d_in[12];
    const float* out_b = (const float*)d_in[13];
    const float* trans = (const float*)d_in[14];
    const float* start_trans = (const float*)d_in[15];
    const float* end_trans = (const float*)d_in[16];

    char* ws = (char*)d_ws;
    u16* emb = (u16*)(ws + O_EMB);
    u16* xg = (u16*)(ws + O_XG);
    u16* hs = (u16*)(ws + O_HS);
    float* logits = (float*)(ws + O_LOGITS);
    u16* WhT = (u16*)(ws + O_LOGITS);    // parked in logits region; dead before k4 writes logits
    u16* WiT = (u16*)(ws + O_WIT);
    u16* outWb = (u16*)(ws + O_OUTW);

    hipLaunchKernelGGL(k0_prep, dim3(4160), dim3(256), 0, stream, Wi_f, Wi_b, Wh_f, Wh_b, out_W, WiT, WhT, outWb);
    hipLaunchKernelGGL(k1_embed, dim3(8192), dim3(256), 0, stream, chars, bigrams, char_table, bigram_table, emb);
    hipLaunchKernelGGL(k2_gemm, dim3(256, 16, 2), dim3(256), 0, stream, emb, WiT, b_f, b_b, xg);
    hipLaunchKernelGGL(k3_lstm, dim3(4), dim3(1024), 0, stream, xg, WhT, seq_len, hs);
    hipLaunchKernelGGL(k4_proj, dim3(2048), dim3(256), 0, stream, hs, outWb, out_b, logits);
    hipLaunchKernelGGL(k5_crf, dim3(32), dim3(256), 0, stream, logits, target, seq_len, trans, start_trans, end_trans,
                       (float*)d_out);
}

// Round 2
// 3759.320 us; speedup vs baseline: 1.4215x; 1.4215x over previous
//
#include <hip/hip_runtime.h>
#include <cstdint>
#include <cstddef>

typedef unsigned short u16;
typedef unsigned int u32;
typedef unsigned long long u64;

typedef short short8 __attribute__((ext_vector_type(8)));
typedef float floatx4 __attribute__((ext_vector_type(4)));
typedef u64 u64x2 __attribute__((ext_vector_type(2)));

// Problem constants: B=32, T=512, D=256, H=256, 4H=1024, C=32
// Workspace layout (bytes)
#define O_EMB    0ull                 // emb bf16 [16384][256]
#define O_XG     8388608ull           // xg bf16 [2][512][256 dim][2 half][4 lq][4 gate] u64-of-4-batches
#define O_HS     75497472ull          // hs bf16 [2][16384][256]
#define O_LOGITS 92340224ull          // logits f32 [16384][32]; ALSO WhT bf16 [2][1024][256] (live k0->k3 only)
#define O_WIT    94437504ull          // WiT bf16 [2][1024][256]
#define O_OUTW   95486080ull          // outW bf16 [512][32]
#define WS_NEED  95520896ull

__device__ __forceinline__ u16 f2bf(float x) {
    u32 u = __float_as_uint(x);
    u += 0x7fffu + ((u >> 16) & 1u);
    return (u16)(u >> 16);
}
__device__ __forceinline__ float bf2f(u16 v) { return __uint_as_float(((u32)v) << 16); }
__device__ __forceinline__ float sigm(float x) { return 1.0f / (1.0f + __expf(-x)); }
__device__ __forceinline__ float tanh_f(float x) {
    x = fminf(30.0f, fmaxf(-30.0f, x));
    float e = __expf(-2.0f * x);
    return (1.0f - e) / (1.0f + e);
}

// ---------------- K0: Wi/Wh -> transposed bf16 [n][k], out_W -> bf16 ---------------
__global__ __launch_bounds__(256) void k0_prep(const float* __restrict__ Wi_f, const float* __restrict__ Wi_b,
                                               const float* __restrict__ Wh_f, const float* __restrict__ Wh_b,
                                               const float* __restrict__ out_W,
                                               u16* __restrict__ WiT, u16* __restrict__ WhT,
                                               u16* __restrict__ outWb) {
    int id = blockIdx.x * 256 + threadIdx.x;   // grid 4160*256 = 1064960 exact
    if (id < 524288) {
        int d = id >> 18;
        int rem = id & 262143;
        int k = rem >> 10;
        int n = rem & 1023;
        const float* Wi = d ? Wi_b : Wi_f;
        WiT[(size_t)d * 262144 + (size_t)n * 256 + k] = f2bf(Wi[(size_t)k * 1024 + n]);
    } else if (id < 540672) {
        int id2 = id - 524288;                 // < 16384
        outWb[id2] = f2bf(out_W[id2]);
    } else {
        int id2 = id - 540672;                 // < 524288
        int d = id2 >> 18;
        int rem = id2 & 262143;
        int k = rem >> 10;
        int n = rem & 1023;
        const float* Wh = d ? Wh_b : Wh_f;
        WhT[(size_t)d * 262144 + (size_t)n * 256 + k] = f2bf(Wh[(size_t)k * 1024 + n]);
    }
}

// ---------------- K1: embedding gather -> emb bf16 [r=t*32+b][256] -----------------
__global__ __launch_bounds__(256) void k1_embed(const int* __restrict__ chars, const int* __restrict__ bigrams,
                                                const float* __restrict__ ct, const float* __restrict__ bt,
                                                u16* __restrict__ emb) {
    int idx = blockIdx.x * 256 + threadIdx.x;  // grid 8192*256 = 2097152 = 16384*128
    int r = idx >> 7;
    int p2 = (idx & 127) << 1;
    int t = r >> 5, b = r & 31;
    const float* src;
    if (p2 < 128) src = ct + (size_t)chars[b * 512 + t] * 128 + p2;
    else          src = bt + (size_t)bigrams[b * 512 + t] * 128 + (p2 - 128);
    float2 v = *(const float2*)(const void*)src;
    u32 pk = (u32)f2bf(v.x) | ((u32)f2bf(v.y) << 16);
    *(u32*)(void*)(emb + (size_t)r * 256 + p2) = pk;
}

// ---------------- K2: xg = emb @ Wi_d + b_d  (bf16 MFMA) ---------------------------
// Store layout: u64 index = (((t*256 + c)*2 + half)*4 + lq)*4 + g  (4 batches/u64)
// so k3's 4 gate-words per thread are 32B contiguous.
__global__ __launch_bounds__(256) void k2_gemm(const u16* __restrict__ emb, const u16* __restrict__ WiT,
                                               const float* __restrict__ b_f, const float* __restrict__ b_b,
                                               u16* __restrict__ xg) {
    int mbase = blockIdx.x * 64;
    int nbase = blockIdx.y * 64;
    int d = blockIdx.z;
    const u16* Bt = WiT + (size_t)d * 262144;
    const float* bias = d ? b_b : b_f;
    u64* xgd = (u64*)(void*)(xg + (size_t)d * 16777216ull);
    int tid = threadIdx.x;
    int wv = tid >> 6, l = tid & 63, lm = l & 15, lq = l >> 4;
    floatx4 acc[4] = {{0,0,0,0},{0,0,0,0},{0,0,0,0},{0,0,0,0}};
    int arow = mbase + wv * 16 + lm;
#pragma unroll
    for (int kc = 0; kc < 8; ++kc) {
        int k0 = kc * 32 + lq * 8;
        short8 a = *(const short8*)(const void*)(emb + (size_t)arow * 256 + k0);
#pragma unroll
        for (int nt = 0; nt < 4; ++nt) {
            short8 bb = *(const short8*)(const void*)(Bt + (size_t)(nbase + nt * 16 + lm) * 256 + k0);
            acc[nt] = __builtin_amdgcn_mfma_f32_16x16x32_bf16(a, bb, acc[nt], 0, 0, 0);
        }
    }
    // rows rr0..rr0+3 lie in one 32-row (one t) block since mbase is 64-aligned
    int rr0 = mbase + wv * 16 + lq * 4;
    int tt = rr0 >> 5, b0 = rr0 & 31;
    int half = b0 >> 4, lqq = (b0 >> 2) & 3;
#pragma unroll
    for (int nt = 0; nt < 4; ++nt) {
        int n = nbase + nt * 16 + lm;
        int g = n >> 8, c = n & 255;
        float bv = bias[n];
        u64 pk = (u64)f2bf(acc[nt][0] + bv)
               | ((u64)f2bf(acc[nt][1] + bv) << 16)
               | ((u64)f2bf(acc[nt][2] + bv) << 32)
               | ((u64)f2bf(acc[nt][3] + bv) << 48);
        xgd[((((size_t)tt * 256 + c) * 2 + half) * 4 + lqq) * 4 + g] = pk;
    }
}

// ---------------- K3: BiLSTM recurrence, batch-split (NO inter-block sync) ---------
// 4 blocks: (dir = bid>>1, half = bid&1). 1024 threads = 16 waves, VGPR cap 128.
// Wh register budget is the binding constraint: gates 0..2 B-frags in VGPRs
// (96 regs), gate 3 B-frags staged to LDS in per-lane fragment order (128 KB,
// canonical contiguous ds_read_b128 per kc). xg is folded into the MFMA
// accumulator init (no held xq regs). h exchanged via double-buffered LDS; one
// s_barrier + lgkmcnt(0) per step; global hs history stores left in flight.
__global__ __launch_bounds__(1024) void k3_lstm(const u16* __restrict__ xg, const u16* __restrict__ WhT,
                                                const int* __restrict__ seq_len, u16* __restrict__ hs) {
    int bid = blockIdx.x;
    int dir = bid >> 1;
    int half = bid & 1;
    const char* xgb = (const char*)xg + (size_t)dir * 33554432ull;   // 32MB per dir
    const u16* whd = WhT + (size_t)dir * 262144ull;
    u16* hsd = hs + (size_t)dir * 4194304ull;

    __shared__ __align__(16) u16 wh3[65536];        // 128 KB: g=3 B-frags [wv][kc][lane]
    __shared__ __align__(16) u16 h_all[2][4224];    // 16.5 KB: h dbuf [batch16][pitch 264]

    int tid = threadIdx.x;
    int wv = tid >> 6;
    int l = tid & 63;
    int lm = l & 15, lq = l >> 4;
    int c_dim = wv * 16 + lm;

    // B-frags for gates 0..2 in VGPRs (96 regs)
    short8 whb[3][8];
#pragma unroll
    for (int g = 0; g < 3; ++g)
#pragma unroll
        for (int kc = 0; kc < 8; ++kc)
            whb[g][kc] = *(const short8*)(const void*)(whd + (size_t)(g * 256 + c_dim) * 256 + kc * 32 + lq * 8);
    // gate 3 B-frags -> LDS, per-lane fragment order (contiguous 1KB per wave-read)
#pragma unroll
    for (int kc = 0; kc < 8; ++kc) {
        short8 f3 = *(const short8*)(const void*)(whd + (size_t)(768 + c_dim) * 256 + kc * 32 + lq * 8);
        ((short8*)(void*)wh3)[(wv * 8 + kc) * 64 + l] = f3;
    }

    float cst[4] = {0.f, 0.f, 0.f, 0.f};
    u32 Lp0, Lp1;
    {
        int L0 = seq_len[half * 16 + lq * 4 + 0];
        int L1 = seq_len[half * 16 + lq * 4 + 1];
        int L2 = seq_len[half * 16 + lq * 4 + 2];
        int L3 = seq_len[half * 16 + lq * 4 + 3];
        Lp0 = (u32)L0 | ((u32)L1 << 16);
        Lp1 = (u32)L2 | ((u32)L3 << 16);
    }

    for (int i = tid; i < 4224; i += 1024) h_all[0][i] = 0;   // h_{-1} = 0
    __syncthreads();

    const int aoff = lm * 264 + lq * 8;   // A-frag: row=batch lm, k=kc*32+lq*8..+8
    const int hrow = lq * 4;
    // per-thread xg byte offset (t part added per step): 4 gate-u64s contiguous (32B)
    const size_t xthr = ((((size_t)c_dim * 2 + half) * 4 + lq) * 4) * 8;

    for (int s = 0; s < 512; ++s) {
        int t = dir ? (511 - s) : s;
        const u64* xp = (const u64*)(const void*)(xgb + (size_t)t * 65536 + xthr);
        u64x2 x01 = *(const u64x2*)(const void*)(xp);
        u64x2 x23 = *(const u64x2*)(const void*)(xp + 2);
        floatx4 acc0, acc1, acc2, acc3;
#pragma unroll
        for (int r = 0; r < 4; ++r) {
            acc0[r] = bf2f((u16)(x01.x >> (16 * r)));
            acc1[r] = bf2f((u16)(x01.y >> (16 * r)));
            acc2[r] = bf2f((u16)(x23.x >> (16 * r)));
            acc3[r] = bf2f((u16)(x23.y >> (16 * r)));
        }

        const u16* hb = h_all[s & 1];
#pragma unroll
        for (int kc = 0; kc < 8; ++kc) {
            short8 b3 = ((const short8*)(const void*)wh3)[(wv * 8 + kc) * 64 + l];
            short8 a = *(const short8*)(const void*)(hb + aoff + kc * 32);
            acc0 = __builtin_amdgcn_mfma_f32_16x16x32_bf16(a, whb[0][kc], acc0, 0, 0, 0);
            acc1 = __builtin_amdgcn_mfma_f32_16x16x32_bf16(a, whb[1][kc], acc1, 0, 0, 0);
            acc2 = __builtin_amdgcn_mfma_f32_16x16x32_bf16(a, whb[2][kc], acc2, 0, 0, 0);
            acc3 = __builtin_amdgcn_mfma_f32_16x16x32_bf16(a, b3, acc3, 0, 0, 0);
        }

        u16* hw = h_all[(s & 1) ^ 1];
        u16* hsrow = hsd + ((size_t)(t * 32 + half * 16 + hrow)) * 256 + c_dim;
#pragma unroll
        for (int r = 0; r < 4; ++r) {
            float ig = sigm(acc0[r]);
            float fg = sigm(acc1[r]);
            float gt = tanh_f(acc2[r]);
            float og = sigm(acc3[r]);
            float cn = fg * cst[r] + ig * gt;
            float hn = og * tanh_f(cn);
            int Lv = (int)(((r < 2) ? (Lp0 >> (16 * (r & 1))) : (Lp1 >> (16 * (r & 1)))) & 0xffffu);
            if (dir && t >= Lv) { cn = cst[r]; hn = 0.0f; }   // backward: masked suffix stays 0
            cst[r] = cn;
            u16 hbf = f2bf(hn);
            hw[(hrow + r) * 264 + c_dim] = hbf;               // h for next step (LDS)
            hsrow[(size_t)r * 256] = hbf;                     // history for k4 (left in flight)
        }
        // Barrier WITHOUT vmcnt drain: only LDS writes must be visible.
        asm volatile("s_waitcnt lgkmcnt(0)" ::: "memory");
        __builtin_amdgcn_sched_barrier(0);
        __builtin_amdgcn_s_barrier();
        __builtin_amdgcn_sched_barrier(0);
    }
}

// ---------------- K4: logits = log_softmax([hf;hb] @ out_W + out_b) ---------------
__global__ __launch_bounds__(256) void k4_proj(const u16* __restrict__ hs, const u16* __restrict__ outWb,
                                               const float* __restrict__ out_b, float* __restrict__ logits) {
    int r = blockIdx.x * 8 + (threadIdx.x >> 5);
    int n = threadIdx.x & 31;
    const u16* hf = hs + (size_t)r * 256;
    const u16* hbk = hs + 4194304ull + (size_t)r * 256;
    float acc = out_b[n];
#pragma unroll 4
    for (int k = 0; k < 256; k += 2) {
        u32 hv = *(const u32*)(const void*)(hf + k);
        acc += bf2f((u16)hv) * bf2f(outWb[k * 32 + n]);
        acc += bf2f((u16)(hv >> 16)) * bf2f(outWb[(k + 1) * 32 + n]);
    }
#pragma unroll 4
    for (int k = 0; k < 256; k += 2) {
        u32 hv = *(const u32*)(const void*)(hbk + k);
        acc += bf2f((u16)hv) * bf2f(outWb[(256 + k) * 32 + n]);
        acc += bf2f((u16)(hv >> 16)) * bf2f(outWb[(257 + k) * 32 + n]);
    }
    float m = acc;
#pragma unroll
    for (int d2 = 16; d2 >= 1; d2 >>= 1) m = fmaxf(m, __shfl_xor(m, d2, 32));
    float s = __expf(acc - m);
#pragma unroll
    for (int d2 = 16; d2 >= 1; d2 >>= 1) s += __shfl_xor(s, d2, 32);
    logits[(size_t)r * 32 + n] = acc - m - __logf(s);
}

// ---------------- K5: CRF forward + gold score -> out[b] --------------------------
__global__ __launch_bounds__(256) void k5_crf(const float* __restrict__ logits, const int* __restrict__ target,
                                              const int* __restrict__ seq_len, const float* __restrict__ trans,
                                              const float* __restrict__ start_trans, const float* __restrict__ end_trans,
                                              float* __restrict__ out) {
    int b = blockIdx.x;
    int tid = threadIdx.x;
    int L = seq_len[b];
    __shared__ float alpha[32];
    __shared__ float red[4];
    __shared__ float goldsh;

    // gold path score
    float part = 0.0f;
    for (int t = tid; t < 512; t += 256) {
        if (t < L) {
            int tg = target[b * 512 + t];
            part += logits[((size_t)(t * 32 + b)) * 32 + tg];
            if (t >= 1) part += trans[target[b * 512 + t - 1] * 32 + tg];
        }
    }
#pragma unroll
    for (int d2 = 32; d2 >= 1; d2 >>= 1) part += __shfl_xor(part, d2, 64);
    if ((tid & 63) == 0) red[tid >> 6] = part;
    __syncthreads();
    if (tid == 0) {
        float g = red[0] + red[1] + red[2] + red[3];
        g += start_trans[target[b * 512]];
        g += end_trans[target[b * 512 + L - 1]];
        goldsh = g;
    }
    if (tid < 32) alpha[tid] = logits[(size_t)b * 32 + tid] + start_trans[tid];
    __syncthreads();

    int j = tid >> 3, uu = tid & 7;
    float tr4[4];
#pragma unroll
    for (int r = 0; r < 4; ++r) tr4[r] = trans[(uu * 4 + r) * 32 + j];
    float e_next = logits[((size_t)(32 + b)) * 32 + j];
    for (int t = 1; t < 512; ++t) {
        float e = e_next;
        if (t < 511) e_next = logits[((size_t)((t + 1) * 32 + b)) * 32 + j];
        float a0 = alpha[uu * 4 + 0] + tr4[0];
        float a1 = alpha[uu * 4 + 1] + tr4[1];
        float a2 = alpha[uu * 4 + 2] + tr4[2];
        float a3 = alpha[uu * 4 + 3] + tr4[3];
        float m = fmaxf(fmaxf(a0, a1), fmaxf(a2, a3));
#pragma unroll
        for (int d2 = 4; d2 >= 1; d2 >>= 1) m = fmaxf(m, __shfl_xor(m, d2, 8));
        float ss = __expf(a0 - m) + __expf(a1 - m) + __expf(a2 - m) + __expf(a3 - m);
#pragma unroll
        for (int d2 = 4; d2 >= 1; d2 >>= 1) ss += __shfl_xor(ss, d2, 8);
        float nv = e + m + __logf(ss);
        __syncthreads();
        if (uu == 0 && t < L) alpha[j] = nv;
        __syncthreads();
    }
    if (tid < 32) {
        float v = alpha[tid] + end_trans[tid];
        float m = v;
#pragma unroll
        for (int d2 = 16; d2 >= 1; d2 >>= 1) m = fmaxf(m, __shfl_xor(m, d2, 32));
        float s2 = __expf(v - m);
#pragma unroll
        for (int d2 = 16; d2 >= 1; d2 >>= 1) s2 += __shfl_xor(s2, d2, 32);
        if (tid == 0) out[b] = m + __logf(s2) - goldsh;
    }
}

extern "C" void kernel_launch(void* const* d_in, const int* in_sizes, int n_in,
                              void* d_out, int out_size, void* d_ws, size_t ws_size,
                              hipStream_t stream) {
    if (ws_size < WS_NEED) return;  // workspace too small: fail cleanly, no OOB
    const int* chars = (const int*)d_in[0];
    const int* bigrams = (const int*)d_in[1];
    const int* seq_len = (const int*)d_in[2];
    const int* target = (const int*)d_in[3];
    const float* char_table = (const float*)d_in[4];
    const float* bigram_table = (const float*)d_in[5];
    const float* Wi_f = (const float*)d_in[6];
    const float* Wh_f = (const float*)d_in[7];
    const float* b_f = (const float*)d_in[8];
    const float* Wi_b = (const float*)d_in[9];
    const float* Wh_b = (const float*)d_in[10];
    const float* b_b = (const float*)d_in[11];
    const float* out_W = (const float*)d_in[12];
    const float* out_b = (const float*)d_in[13];
    const float* trans = (const float*)d_in[14];
    const float* start_trans = (const float*)d_in[15];
    const float* end_trans = (const float*)d_in[16];

    char* ws = (char*)d_ws;
    u16* emb = (u16*)(ws + O_EMB);
    u16* xg = (u16*)(ws + O_XG);
    u16* hs = (u16*)(ws + O_HS);
    float* logits = (float*)(ws + O_LOGITS);
    u16* WhT = (u16*)(ws + O_LOGITS);    // parked in logits region; dead before k4 writes logits
    u16* WiT = (u16*)(ws + O_WIT);
    u16* outWb = (u16*)(ws + O_OUTW);

    hipLaunchKernelGGL(k0_prep, dim3(4160), dim3(256), 0, stream, Wi_f, Wi_b, Wh_f, Wh_b, out_W, WiT, WhT, outWb);
    hipLaunchKernelGGL(k1_embed, dim3(8192), dim3(256), 0, stream, chars, bigrams, char_table, bigram_table, emb);
    hipLaunchKernelGGL(k2_gemm, dim3(256, 16, 2), dim3(256), 0, stream, emb, WiT, b_f, b_b, xg);
    hipLaunchKernelGGL(k3_lstm, dim3(4), dim3(1024), 0, stream, xg, WhT, seq_len, hs);
    hipLaunchKernelGGL(k4_proj, dim3(2048), dim3(256), 0, stream, hs, outWb, out_b, logits);
    hipLaunchKernelGGL(k5_crf, dim3(32), dim3(256), 0, stream, logits, target, seq_len, trans, start_trans, end_trans,
                       (float*)d_out);
}

// Round 3
// 3617.617 us; speedup vs baseline: 1.4772x; 1.0392x over previous
//
#include <hip/hip_runtime.h>
#include <cstdint>
#include <cstddef>

typedef unsigned short u16;
typedef unsigned int u32;
typedef unsigned long long u64;

typedef short short8 __attribute__((ext_vector_type(8)));
typedef float floatx4 __attribute__((ext_vector_type(4)));
typedef u64 u64x2 __attribute__((ext_vector_type(2)));

// Problem constants: B=32, T=512, D=256, H=256, 4H=1024, C=32
// Workspace layout (bytes)
#define O_EMB    0ull                 // emb bf16 [16384][256]
#define O_XG     8388608ull           // xg bf16 [2][512][256 dim][2 half][4 lq][4 gate] u64-of-4-batches
#define O_HS     75497472ull          // hs bf16 [2][16384][256]
#define O_LOGITS 92340224ull          // logits f32 [16384][32]; ALSO WhT bf16 [2][1024][256] (live k0->k3 only)
#define O_WIT    94437504ull          // WiT bf16 [2][1024][256]
#define O_OUTW   95486080ull          // outW bf16 [512][32]
#define WS_NEED  95520896ull

__device__ __forceinline__ u16 f2bf(float x) {
    u32 u = __float_as_uint(x);
    u += 0x7fffu + ((u >> 16) & 1u);
    return (u16)(u >> 16);
}
__device__ __forceinline__ float bf2f(u16 v) { return __uint_as_float(((u32)v) << 16); }
__device__ __forceinline__ float sigm(float x) { return 1.0f / (1.0f + __expf(-x)); }
__device__ __forceinline__ float tanh_f(float x) {
    x = fminf(30.0f, fmaxf(-30.0f, x));
    float e = __expf(-2.0f * x);
    return (1.0f - e) / (1.0f + e);
}

// ---------------- K0: Wi/Wh -> transposed bf16 [n][k], out_W -> bf16 ---------------
__global__ __launch_bounds__(256) void k0_prep(const float* __restrict__ Wi_f, const float* __restrict__ Wi_b,
                                               const float* __restrict__ Wh_f, const float* __restrict__ Wh_b,
                                               const float* __restrict__ out_W,
                                               u16* __restrict__ WiT, u16* __restrict__ WhT,
                                               u16* __restrict__ outWb) {
    int id = blockIdx.x * 256 + threadIdx.x;   // grid 4160*256 = 1064960 exact
    if (id < 524288) {
        int d = id >> 18;
        int rem = id & 262143;
        int k = rem >> 10;
        int n = rem & 1023;
        const float* Wi = d ? Wi_b : Wi_f;
        WiT[(size_t)d * 262144 + (size_t)n * 256 + k] = f2bf(Wi[(size_t)k * 1024 + n]);
    } else if (id < 540672) {
        int id2 = id - 524288;                 // < 16384
        outWb[id2] = f2bf(out_W[id2]);
    } else {
        int id2 = id - 540672;                 // < 524288
        int d = id2 >> 18;
        int rem = id2 & 262143;
        int k = rem >> 10;
        int n = rem & 1023;
        const float* Wh = d ? Wh_b : Wh_f;
        WhT[(size_t)d * 262144 + (size_t)n * 256 + k] = f2bf(Wh[(size_t)k * 1024 + n]);
    }
}

// ---------------- K1: embedding gather -> emb bf16 [r=t*32+b][256] -----------------
__global__ __launch_bounds__(256) void k1_embed(const int* __restrict__ chars, const int* __restrict__ bigrams,
                                                const float* __restrict__ ct, const float* __restrict__ bt,
                                                u16* __restrict__ emb) {
    int idx = blockIdx.x * 256 + threadIdx.x;  // grid 8192*256 = 2097152 = 16384*128
    int r = idx >> 7;
    int p2 = (idx & 127) << 1;
    int t = r >> 5, b = r & 31;
    const float* src;
    if (p2 < 128) src = ct + (size_t)chars[b * 512 + t] * 128 + p2;
    else          src = bt + (size_t)bigrams[b * 512 + t] * 128 + (p2 - 128);
    float2 v = *(const float2*)(const void*)src;
    u32 pk = (u32)f2bf(v.x) | ((u32)f2bf(v.y) << 16);
    *(u32*)(void*)(emb + (size_t)r * 256 + p2) = pk;
}

// ---------------- K2: xg = emb @ Wi_d + b_d  (bf16 MFMA) ---------------------------
// Store layout: u64 index = (((t*256 + c)*2 + half)*4 + lq)*4 + g  (4 batches/u64)
// so k3's 4 gate-words per thread are 32B contiguous.
__global__ __launch_bounds__(256) void k2_gemm(const u16* __restrict__ emb, const u16* __restrict__ WiT,
                                               const float* __restrict__ b_f, const float* __restrict__ b_b,
                                               u16* __restrict__ xg) {
    int mbase = blockIdx.x * 64;
    int nbase = blockIdx.y * 64;
    int d = blockIdx.z;
    const u16* Bt = WiT + (size_t)d * 262144;
    const float* bias = d ? b_b : b_f;
    u64* xgd = (u64*)(void*)(xg + (size_t)d * 16777216ull);
    int tid = threadIdx.x;
    int wv = tid >> 6, l = tid & 63, lm = l & 15, lq = l >> 4;
    floatx4 acc[4] = {{0,0,0,0},{0,0,0,0},{0,0,0,0},{0,0,0,0}};
    int arow = mbase + wv * 16 + lm;
#pragma unroll
    for (int kc = 0; kc < 8; ++kc) {
        int k0 = kc * 32 + lq * 8;
        short8 a = *(const short8*)(const void*)(emb + (size_t)arow * 256 + k0);
#pragma unroll
        for (int nt = 0; nt < 4; ++nt) {
            short8 bb = *(const short8*)(const void*)(Bt + (size_t)(nbase + nt * 16 + lm) * 256 + k0);
            acc[nt] = __builtin_amdgcn_mfma_f32_16x16x32_bf16(a, bb, acc[nt], 0, 0, 0);
        }
    }
    // rows rr0..rr0+3 lie in one 32-row (one t) block since mbase is 64-aligned
    int rr0 = mbase + wv * 16 + lq * 4;
    int tt = rr0 >> 5, b0 = rr0 & 31;
    int half = b0 >> 4, lqq = (b0 >> 2) & 3;
#pragma unroll
    for (int nt = 0; nt < 4; ++nt) {
        int n = nbase + nt * 16 + lm;
        int g = n >> 8, c = n & 255;
        float bv = bias[n];
        u64 pk = (u64)f2bf(acc[nt][0] + bv)
               | ((u64)f2bf(acc[nt][1] + bv) << 16)
               | ((u64)f2bf(acc[nt][2] + bv) << 32)
               | ((u64)f2bf(acc[nt][3] + bv) << 48);
        xgd[((((size_t)tt * 256 + c) * 2 + half) * 4 + lqq) * 4 + g] = pk;
    }
}

// ---------------- K3: BiLSTM recurrence, batch-split (NO inter-block sync) ---------
// 4 blocks: (dir = bid>>1, half = bid&1). 512 threads = 8 waves.
// __launch_bounds__(512, 2) -> VGPR cap 256/wave. Each wave owns 128 gate-cols
// (32 per gate = 2 n-tiles). Gates 0..2 B-frags in VGPRs (192 regs); gate 3
// B-frags in LDS (128 KB, per-lane fragment order -> contiguous ds_read_b128).
// acc[4][2] (32) + cst[2][4] (8) + transients ~= 250 total, inside the 256 cap.
// h exchanged via double-buffered LDS; one s_barrier + lgkmcnt(0) per step;
// global hs history stores left in flight across the barrier.
__global__ __launch_bounds__(512, 2) void k3_lstm(const u16* __restrict__ xg, const u16* __restrict__ WhT,
                                                  const int* __restrict__ seq_len, u16* __restrict__ hs) {
    int bid = blockIdx.x;
    int dir = bid >> 1;
    int half = bid & 1;
    const char* xgb = (const char*)xg + (size_t)dir * 33554432ull;   // 32MB per dir
    const u16* whd = WhT + (size_t)dir * 262144ull;
    u16* hsd = hs + (size_t)dir * 4194304ull;

    __shared__ __align__(16) u16 wh3[65536];        // 128 KB: g=3 B-frags [wv][nt][kc][lane]
    __shared__ __align__(16) u16 h_all[2][4224];    // 16.5 KB: h dbuf [batch16][pitch 264]

    int tid = threadIdx.x;
    int wv = tid >> 6;                              // 0..7
    int l = tid & 63;
    int lm = l & 15, lq = l >> 4;
    int cbase = wv * 32 + lm;                       // nt=0 col; nt=1 col = cbase+16

    // B-frags for gates 0..2 in VGPRs: whb[g][nt][kc] (192 regs)
    short8 whb[3][2][8];
#pragma unroll
    for (int g = 0; g < 3; ++g)
#pragma unroll
        for (int nt = 0; nt < 2; ++nt)
#pragma unroll
            for (int kc = 0; kc < 8; ++kc)
                whb[g][nt][kc] = *(const short8*)(const void*)(
                    whd + (size_t)(g * 256 + cbase + nt * 16) * 256 + kc * 32 + lq * 8);
    // gate 3 B-frags -> LDS, per-lane fragment order (contiguous 1KB per wave-read)
#pragma unroll
    for (int nt = 0; nt < 2; ++nt)
#pragma unroll
        for (int kc = 0; kc < 8; ++kc) {
            short8 f3 = *(const short8*)(const void*)(
                whd + (size_t)(768 + cbase + nt * 16) * 256 + kc * 32 + lq * 8);
            ((short8*)(void*)wh3)[((wv * 2 + nt) * 8 + kc) * 64 + l] = f3;
        }

    float cst[2][4] = {{0.f, 0.f, 0.f, 0.f}, {0.f, 0.f, 0.f, 0.f}};
    u32 Lp0, Lp1;
    {
        int L0 = seq_len[half * 16 + lq * 4 + 0];
        int L1 = seq_len[half * 16 + lq * 4 + 1];
        int L2 = seq_len[half * 16 + lq * 4 + 2];
        int L3 = seq_len[half * 16 + lq * 4 + 3];
        Lp0 = (u32)L0 | ((u32)L1 << 16);
        Lp1 = (u32)L2 | ((u32)L3 << 16);
    }

    for (int i = tid; i < 4224; i += 512) h_all[0][i] = 0;   // h_{-1} = 0
    __syncthreads();

    const int aoff = lm * 264 + lq * 8;   // A-frag: row=batch lm, k=kc*32+lq*8..+8
    const int hrow = lq * 4;
    // per-thread xg byte offsets (t part added per step): per nt, 4 gate-u64s = 32B
    const size_t xthr0 = ((((size_t)cbase * 2 + half) * 4 + lq) * 4) * 8;
    const size_t xthr1 = ((((size_t)(cbase + 16) * 2 + half) * 4 + lq) * 4) * 8;

    for (int s = 0; s < 512; ++s) {
        int t = dir ? (511 - s) : s;
        const char* xrow = xgb + (size_t)t * 65536;
        u64x2 xa = *(const u64x2*)(const void*)(xrow + xthr0);        // nt0 gates 0,1
        u64x2 xb = *(const u64x2*)(const void*)(xrow + xthr0 + 16);   // nt0 gates 2,3
        u64x2 xc = *(const u64x2*)(const void*)(xrow + xthr1);        // nt1 gates 0,1
        u64x2 xd = *(const u64x2*)(const void*)(xrow + xthr1 + 16);   // nt1 gates 2,3

        floatx4 acc[4][2];
#pragma unroll
        for (int r = 0; r < 4; ++r) {
            acc[0][0][r] = bf2f((u16)(xa.x >> (16 * r)));
            acc[1][0][r] = bf2f((u16)(xa.y >> (16 * r)));
            acc[2][0][r] = bf2f((u16)(xb.x >> (16 * r)));
            acc[3][0][r] = bf2f((u16)(xb.y >> (16 * r)));
            acc[0][1][r] = bf2f((u16)(xc.x >> (16 * r)));
            acc[1][1][r] = bf2f((u16)(xc.y >> (16 * r)));
            acc[2][1][r] = bf2f((u16)(xd.x >> (16 * r)));
            acc[3][1][r] = bf2f((u16)(xd.y >> (16 * r)));
        }

        const u16* hb = h_all[s & 1];
#pragma unroll
        for (int kc = 0; kc < 8; ++kc) {
            short8 a = *(const short8*)(const void*)(hb + aoff + kc * 32);
            short8 b30 = ((const short8*)(const void*)wh3)[((wv * 2 + 0) * 8 + kc) * 64 + l];
            short8 b31 = ((const short8*)(const void*)wh3)[((wv * 2 + 1) * 8 + kc) * 64 + l];
            acc[0][0] = __builtin_amdgcn_mfma_f32_16x16x32_bf16(a, whb[0][0][kc], acc[0][0], 0, 0, 0);
            acc[0][1] = __builtin_amdgcn_mfma_f32_16x16x32_bf16(a, whb[0][1][kc], acc[0][1], 0, 0, 0);
            acc[1][0] = __builtin_amdgcn_mfma_f32_16x16x32_bf16(a, whb[1][0][kc], acc[1][0], 0, 0, 0);
            acc[1][1] = __builtin_amdgcn_mfma_f32_16x16x32_bf16(a, whb[1][1][kc], acc[1][1], 0, 0, 0);
            acc[2][0] = __builtin_amdgcn_mfma_f32_16x16x32_bf16(a, whb[2][0][kc], acc[2][0], 0, 0, 0);
            acc[2][1] = __builtin_amdgcn_mfma_f32_16x16x32_bf16(a, whb[2][1][kc], acc[2][1], 0, 0, 0);
            acc[3][0] = __builtin_amdgcn_mfma_f32_16x16x32_bf16(a, b30, acc[3][0], 0, 0, 0);
            acc[3][1] = __builtin_amdgcn_mfma_f32_16x16x32_bf16(a, b31, acc[3][1], 0, 0, 0);
        }

        u16* hw = h_all[(s & 1) ^ 1];
        // one 32-bit element-offset base for the 8 global hs stores (imm-foldable)
        u16* hsbase = hsd + ((size_t)(t * 32 + half * 16 + hrow)) * 256 + cbase;
#pragma unroll
        for (int nt = 0; nt < 2; ++nt) {
#pragma unroll
            for (int r = 0; r < 4; ++r) {
                float ig = sigm(acc[0][nt][r]);
                float fg = sigm(acc[1][nt][r]);
                float gt = tanh_f(acc[2][nt][r]);
                float og = sigm(acc[3][nt][r]);
                float cn = fg * cst[nt][r] + ig * gt;
                float hn = og * tanh_f(cn);
                int Lv = (int)(((r < 2) ? (Lp0 >> (16 * (r & 1))) : (Lp1 >> (16 * (r & 1)))) & 0xffffu);
                if (dir && t >= Lv) { cn = cst[nt][r]; hn = 0.0f; }   // backward: masked suffix stays 0
                cst[nt][r] = cn;
                u16 hbf = f2bf(hn);
                hw[(hrow + r) * 264 + cbase + nt * 16] = hbf;          // h for next step (LDS)
                hsbase[(size_t)r * 256 + nt * 16] = hbf;               // history for k4 (in flight)
            }
        }
        // Barrier WITHOUT vmcnt drain: only LDS writes must be visible.
        asm volatile("s_waitcnt lgkmcnt(0)" ::: "memory");
        __builtin_amdgcn_sched_barrier(0);
        __builtin_amdgcn_s_barrier();
        __builtin_amdgcn_sched_barrier(0);
    }
}

// ---------------- K4: logits = log_softmax([hf;hb] @ out_W + out_b) ---------------
__global__ __launch_bounds__(256) void k4_proj(const u16* __restrict__ hs, const u16* __restrict__ outWb,
                                               const float* __restrict__ out_b, float* __restrict__ logits) {
    int r = blockIdx.x * 8 + (threadIdx.x >> 5);
    int n = threadIdx.x & 31;
    const u16* hf = hs + (size_t)r * 256;
    const u16* hbk = hs + 4194304ull + (size_t)r * 256;
    float acc = out_b[n];
#pragma unroll 4
    for (int k = 0; k < 256; k += 2) {
        u32 hv = *(const u32*)(const void*)(hf + k);
        acc += bf2f((u16)hv) * bf2f(outWb[k * 32 + n]);
        acc += bf2f((u16)(hv >> 16)) * bf2f(outWb[(k + 1) * 32 + n]);
    }
#pragma unroll 4
    for (int k = 0; k < 256; k += 2) {
        u32 hv = *(const u32*)(const void*)(hbk + k);
        acc += bf2f((u16)hv) * bf2f(outWb[(256 + k) * 32 + n]);
        acc += bf2f((u16)(hv >> 16)) * bf2f(outWb[(257 + k) * 32 + n]);
    }
    float m = acc;
#pragma unroll
    for (int d2 = 16; d2 >= 1; d2 >>= 1) m = fmaxf(m, __shfl_xor(m, d2, 32));
    float s = __expf(acc - m);
#pragma unroll
    for (int d2 = 16; d2 >= 1; d2 >>= 1) s += __shfl_xor(s, d2, 32);
    logits[(size_t)r * 32 + n] = acc - m - __logf(s);
}

// ---------------- K5: CRF forward + gold score -> out[b] --------------------------
__global__ __launch_bounds__(256) void k5_crf(const float* __restrict__ logits, const int* __restrict__ target,
                                              const int* __restrict__ seq_len, const float* __restrict__ trans,
                                              const float* __restrict__ start_trans, const float* __restrict__ end_trans,
                                              float* __restrict__ out) {
    int b = blockIdx.x;
    int tid = threadIdx.x;
    int L = seq_len[b];
    __shared__ float alpha[32];
    __shared__ float red[4];
    __shared__ float goldsh;

    // gold path score
    float part = 0.0f;
    for (int t = tid; t < 512; t += 256) {
        if (t < L) {
            int tg = target[b * 512 + t];
            part += logits[((size_t)(t * 32 + b)) * 32 + tg];
            if (t >= 1) part += trans[target[b * 512 + t - 1] * 32 + tg];
        }
    }
#pragma unroll
    for (int d2 = 32; d2 >= 1; d2 >>= 1) part += __shfl_xor(part, d2, 64);
    if ((tid & 63) == 0) red[tid >> 6] = part;
    __syncthreads();
    if (tid == 0) {
        float g = red[0] + red[1] + red[2] + red[3];
        g += start_trans[target[b * 512]];
        g += end_trans[target[b * 512 + L - 1]];
        goldsh = g;
    }
    if (tid < 32) alpha[tid] = logits[(size_t)b * 32 + tid] + start_trans[tid];
    __syncthreads();

    int j = tid >> 3, uu = tid & 7;
    float tr4[4];
#pragma unroll
    for (int r = 0; r < 4; ++r) tr4[r] = trans[(uu * 4 + r) * 32 + j];
    float e_next = logits[((size_t)(32 + b)) * 32 + j];
    for (int t = 1; t < 512; ++t) {
        float e = e_next;
        if (t < 511) e_next = logits[((size_t)((t + 1) * 32 + b)) * 32 + j];
        float a0 = alpha[uu * 4 + 0] + tr4[0];
        float a1 = alpha[uu * 4 + 1] + tr4[1];
        float a2 = alpha[uu * 4 + 2] + tr4[2];
        float a3 = alpha[uu * 4 + 3] + tr4[3];
        float m = fmaxf(fmaxf(a0, a1), fmaxf(a2, a3));
#pragma unroll
        for (int d2 = 4; d2 >= 1; d2 >>= 1) m = fmaxf(m, __shfl_xor(m, d2, 8));
        float ss = __expf(a0 - m) + __expf(a1 - m) + __expf(a2 - m) + __expf(a3 - m);
#pragma unroll
        for (int d2 = 4; d2 >= 1; d2 >>= 1) ss += __shfl_xor(ss, d2, 8);
        float nv = e + m + __logf(ss);
        __syncthreads();
        if (uu == 0 && t < L) alpha[j] = nv;
        __syncthreads();
    }
    if (tid < 32) {
        float v = alpha[tid] + end_trans[tid];
        float m = v;
#pragma unroll
        for (int d2 = 16; d2 >= 1; d2 >>= 1) m = fmaxf(m, __shfl_xor(m, d2, 32));
        float s2 = __expf(v - m);
#pragma unroll
        for (int d2 = 16; d2 >= 1; d2 >>= 1) s2 += __shfl_xor(s2, d2, 32);
        if (tid == 0) out[b] = m + __logf(s2) - goldsh;
    }
}

extern "C" void kernel_launch(void* const* d_in, const int* in_sizes, int n_in,
                              void* d_out, int out_size, void* d_ws, size_t ws_size,
                              hipStream_t stream) {
    if (ws_size < WS_NEED) return;  // workspace too small: fail cleanly, no OOB
    const int* chars = (const int*)d_in[0];
    const int* bigrams = (const int*)d_in[1];
    const int* seq_len = (const int*)d_in[2];
    const int* target = (const int*)d_in[3];
    const float* char_table = (const float*)d_in[4];
    const float* bigram_table = (const float*)d_in[5];
    const float* Wi_f = (const float*)d_in[6];
    const float* Wh_f = (const float*)d_in[7];
    const float* b_f = (const float*)d_in[8];
    const float* Wi_b = (const float*)d_in[9];
    const float* Wh_b = (const float*)d_in[10];
    const float* b_b = (const float*)d_in[11];
    const float* out_W = (const float*)d_in[12];
    const float* out_b = (const float*)d_in[13];
    const float* trans = (const float*)d_in[14];
    const float* start_trans = (const float*)d_in[15];
    const float* end_trans = (const float*)d_in[16];

    char* ws = (char*)d_ws;
    u16* emb = (u16*)(ws + O_EMB);
    u16* xg = (u16*)(ws + O_XG);
    u16* hs = (u16*)(ws + O_HS);
    float* logits = (float*)(ws + O_LOGITS);
    u16* WhT = (u16*)(ws + O_LOGITS);    // parked in logits region; dead before k4 writes logits
    u16* WiT = (u16*)(ws + O_WIT);
    u16* outWb = (u16*)(ws + O_OUTW);

    hipLaunchKernelGGL(k0_prep, dim3(4160), dim3(256), 0, stream, Wi_f, Wi_b, Wh_f, Wh_b, out_W, WiT, WhT, outWb);
    hipLaunchKernelGGL(k1_embed, dim3(8192), dim3(256), 0, stream, chars, bigrams, char_table, bigram_table, emb);
    hipLaunchKernelGGL(k2_gemm, dim3(256, 16, 2), dim3(256), 0, stream, emb, WiT, b_f, b_b, xg);
    hipLaunchKernelGGL(k3_lstm, dim3(4), dim3(512), 0, stream, xg, WhT, seq_len, hs);
    hipLaunchKernelGGL(k4_proj, dim3(2048), dim3(256), 0, stream, hs, outWb, out_b, logits);
    hipLaunchKernelGGL(k5_crf, dim3(32), dim3(256), 0, stream, logits, target, seq_len, trans, start_trans, end_trans,
                       (float*)d_out);
}

// Round 4
// 2917.024 us; speedup vs baseline: 1.8320x; 1.2402x over previous
//
#include <hip/hip_runtime.h>
#include <cstdint>
#include <cstddef>

typedef unsigned short u16;
typedef unsigned int u32;
typedef unsigned long long u64;

typedef short short8 __attribute__((ext_vector_type(8)));
typedef float floatx4 __attribute__((ext_vector_type(4)));
typedef u64 u64x2 __attribute__((ext_vector_type(2)));

// Problem constants: B=32, T=512, D=256, H=256, 4H=1024, C=32
// Workspace layout (bytes)
#define O_EMB    0ull                 // emb bf16 [16384][256]
#define O_XG     8388608ull           // xg bf16 [2][512][256 dim][2 half][4 lq][4 gate] u64-of-4-batches
#define O_HS     75497472ull          // hs bf16 [2][16384][256]
#define O_LOGITS 92340224ull          // logits f32 [16384][32]; ALSO WhT bf16 [2][1024][256] (live k0->k3 only)
#define O_WIT    94437504ull          // WiT bf16 [2][1024][256]
#define O_OUTW   95486080ull          // outW bf16 [512][32]
#define WS_NEED  95520896ull

__device__ __forceinline__ u16 f2bf(float x) {
    u32 u = __float_as_uint(x);
    u += 0x7fffu + ((u >> 16) & 1u);
    return (u16)(u >> 16);
}
__device__ __forceinline__ float bf2f(u16 v) { return __uint_as_float(((u32)v) << 16); }
__device__ __forceinline__ float sigm(float x) { return 1.0f / (1.0f + __expf(-x)); }
__device__ __forceinline__ float tanh_f(float x) {
    x = fminf(30.0f, fmaxf(-30.0f, x));
    float e = __expf(-2.0f * x);
    return (1.0f - e) / (1.0f + e);
}

// ---------------- K0: Wi/Wh -> transposed bf16 [n][k], out_W -> bf16 ---------------
__global__ __launch_bounds__(256) void k0_prep(const float* __restrict__ Wi_f, const float* __restrict__ Wi_b,
                                               const float* __restrict__ Wh_f, const float* __restrict__ Wh_b,
                                               const float* __restrict__ out_W,
                                               u16* __restrict__ WiT, u16* __restrict__ WhT,
                                               u16* __restrict__ outWb) {
    int id = blockIdx.x * 256 + threadIdx.x;   // grid 4160*256 = 1064960 exact
    if (id < 524288) {
        int d = id >> 18;
        int rem = id & 262143;
        int k = rem >> 10;
        int n = rem & 1023;
        const float* Wi = d ? Wi_b : Wi_f;
        WiT[(size_t)d * 262144 + (size_t)n * 256 + k] = f2bf(Wi[(size_t)k * 1024 + n]);
    } else if (id < 540672) {
        int id2 = id - 524288;                 // < 16384
        outWb[id2] = f2bf(out_W[id2]);
    } else {
        int id2 = id - 540672;                 // < 524288
        int d = id2 >> 18;
        int rem = id2 & 262143;
        int k = rem >> 10;
        int n = rem & 1023;
        const float* Wh = d ? Wh_b : Wh_f;
        WhT[(size_t)d * 262144 + (size_t)n * 256 + k] = f2bf(Wh[(size_t)k * 1024 + n]);
    }
}

// ---------------- K1: embedding gather -> emb bf16 [r=t*32+b][256] -----------------
__global__ __launch_bounds__(256) void k1_embed(const int* __restrict__ chars, const int* __restrict__ bigrams,
                                                const float* __restrict__ ct, const float* __restrict__ bt,
                                                u16* __restrict__ emb) {
    int idx = blockIdx.x * 256 + threadIdx.x;  // grid 8192*256 = 2097152 = 16384*128
    int r = idx >> 7;
    int p2 = (idx & 127) << 1;
    int t = r >> 5, b = r & 31;
    const float* src;
    if (p2 < 128) src = ct + (size_t)chars[b * 512 + t] * 128 + p2;
    else          src = bt + (size_t)bigrams[b * 512 + t] * 128 + (p2 - 128);
    float2 v = *(const float2*)(const void*)src;
    u32 pk = (u32)f2bf(v.x) | ((u32)f2bf(v.y) << 16);
    *(u32*)(void*)(emb + (size_t)r * 256 + p2) = pk;
}

// ---------------- K2: xg = emb @ Wi_d + b_d  (bf16 MFMA) ---------------------------
// Store layout: u64 index = (((t*256 + c)*2 + half)*4 + lq)*4 + g  (4 batches/u64)
// so k3's 4 gate-words per thread are 32B contiguous.
__global__ __launch_bounds__(256) void k2_gemm(const u16* __restrict__ emb, const u16* __restrict__ WiT,
                                               const float* __restrict__ b_f, const float* __restrict__ b_b,
                                               u16* __restrict__ xg) {
    int mbase = blockIdx.x * 64;
    int nbase = blockIdx.y * 64;
    int d = blockIdx.z;
    const u16* Bt = WiT + (size_t)d * 262144;
    const float* bias = d ? b_b : b_f;
    u64* xgd = (u64*)(void*)(xg + (size_t)d * 16777216ull);
    int tid = threadIdx.x;
    int wv = tid >> 6, l = tid & 63, lm = l & 15, lq = l >> 4;
    floatx4 acc[4] = {{0,0,0,0},{0,0,0,0},{0,0,0,0},{0,0,0,0}};
    int arow = mbase + wv * 16 + lm;
#pragma unroll
    for (int kc = 0; kc < 8; ++kc) {
        int k0 = kc * 32 + lq * 8;
        short8 a = *(const short8*)(const void*)(emb + (size_t)arow * 256 + k0);
#pragma unroll
        for (int nt = 0; nt < 4; ++nt) {
            short8 bb = *(const short8*)(const void*)(Bt + (size_t)(nbase + nt * 16 + lm) * 256 + k0);
            acc[nt] = __builtin_amdgcn_mfma_f32_16x16x32_bf16(a, bb, acc[nt], 0, 0, 0);
        }
    }
    // rows rr0..rr0+3 lie in one 32-row (one t) block since mbase is 64-aligned
    int rr0 = mbase + wv * 16 + lq * 4;
    int tt = rr0 >> 5, b0 = rr0 & 31;
    int half = b0 >> 4, lqq = (b0 >> 2) & 3;
#pragma unroll
    for (int nt = 0; nt < 4; ++nt) {
        int n = nbase + nt * 16 + lm;
        int g = n >> 8, c = n & 255;
        float bv = bias[n];
        u64 pk = (u64)f2bf(acc[nt][0] + bv)
               | ((u64)f2bf(acc[nt][1] + bv) << 16)
               | ((u64)f2bf(acc[nt][2] + bv) << 32)
               | ((u64)f2bf(acc[nt][3] + bv) << 48);
        xgd[((((size_t)tt * 256 + c) * 2 + half) * 4 + lqq) * 4 + g] = pk;
    }
}

// ---------------- K3: BiLSTM recurrence, batch-split (NO inter-block sync) ---------
// 4 blocks: (dir = bid>>1, half = bid&1). 512 threads = 8 waves.
// amdgpu_waves_per_eu(2,2) pins the allocator to a 256-reg/wave budget (LDS at
// 144.5 KB already forces 1 block/CU = 2 waves/EU, so (2,2) costs nothing).
// Peak liveness is kept ~246 < 256 by phase-splitting each step by n-tile:
//   phase nt: acc[4] (16 regs) for gates i,f,g,o of 16 cols; gates 0..2 weights
//   from VGPRs (whb, 192 regs persistent), gate 3 weights from LDS.
// xg software-pipelined: next step's nt0 pair prefetched during phase-1 MFMA.
// h exchanged via double-buffered LDS; one s_barrier + lgkmcnt(0) per step;
// global hs history stores left in flight across the barrier.
__global__ __attribute__((amdgpu_waves_per_eu(2, 2))) __launch_bounds__(512)
void k3_lstm(const u16* __restrict__ xg, const u16* __restrict__ WhT,
             const int* __restrict__ seq_len, u16* __restrict__ hs) {
    int bid = blockIdx.x;
    int dir = bid >> 1;
    int half = bid & 1;
    const char* xgb = (const char*)xg + (size_t)dir * 33554432ull;   // 32MB per dir
    const u16* whd = WhT + (size_t)dir * 262144ull;
    u16* hsd = hs + (size_t)dir * 4194304ull;

    __shared__ __align__(16) u16 wh3[65536];        // 128 KB: g=3 B-frags [wv][nt][kc][lane]
    __shared__ __align__(16) u16 h_all[2][4224];    // 16.5 KB: h dbuf [batch16][pitch 264]

    int tid = threadIdx.x;
    int wv = tid >> 6;                              // 0..7
    int l = tid & 63;
    int lm = l & 15, lq = l >> 4;
    int cbase = wv * 32 + lm;                       // nt=0 col; nt=1 col = cbase+16

    // B-frags for gates 0..2 in VGPRs: whb[g][nt][kc] (192 regs)
    short8 whb[3][2][8];
#pragma unroll
    for (int g = 0; g < 3; ++g)
#pragma unroll
        for (int nt = 0; nt < 2; ++nt)
#pragma unroll
            for (int kc = 0; kc < 8; ++kc)
                whb[g][nt][kc] = *(const short8*)(const void*)(
                    whd + (size_t)(g * 256 + cbase + nt * 16) * 256 + kc * 32 + lq * 8);
    // gate 3 B-frags -> LDS, per-lane fragment order (contiguous 1KB per wave-read)
#pragma unroll
    for (int nt = 0; nt < 2; ++nt)
#pragma unroll
        for (int kc = 0; kc < 8; ++kc) {
            short8 f3 = *(const short8*)(const void*)(
                whd + (size_t)(768 + cbase + nt * 16) * 256 + kc * 32 + lq * 8);
            ((short8*)(void*)wh3)[((wv * 2 + nt) * 8 + kc) * 64 + l] = f3;
        }

    float cs0[4] = {0.f, 0.f, 0.f, 0.f};
    float cs1[4] = {0.f, 0.f, 0.f, 0.f};
    u32 Lp0, Lp1;
    {
        int L0 = seq_len[half * 16 + lq * 4 + 0];
        int L1 = seq_len[half * 16 + lq * 4 + 1];
        int L2 = seq_len[half * 16 + lq * 4 + 2];
        int L3 = seq_len[half * 16 + lq * 4 + 3];
        Lp0 = (u32)L0 | ((u32)L1 << 16);
        Lp1 = (u32)L2 | ((u32)L3 << 16);
    }

    for (int i = tid; i < 4224; i += 512) h_all[0][i] = 0;   // h_{-1} = 0
    __syncthreads();

    const int aoff = lm * 264 + lq * 8;   // A-frag: row=batch lm, k=kc*32+lq*8..+8
    const int hrow = lq * 4;
    // per-thread xg byte offsets (t part added per step): per nt, 4 gate-u64s = 32B
    const size_t xthr0 = ((((size_t)cbase * 2 + half) * 4 + lq) * 4) * 8;
    const size_t xthr1 = ((((size_t)(cbase + 16) * 2 + half) * 4 + lq) * 4) * 8;

    // prologue: prefetch step-0 nt0 xg pair
    int t0 = dir ? 511 : 0;
    u64x2 xa = *(const u64x2*)(const void*)(xgb + (size_t)t0 * 65536 + xthr0);

    for (int s = 0; s < 512; ++s) {
        int t = dir ? (511 - s) : s;
        const char* xrow = xgb + (size_t)t * 65536;

        // ---- phase 0 (cols cbase, nt=0): acc init from prefetched xa ----
        floatx4 aI, aF, aG, aO;
#pragma unroll
        for (int r = 0; r < 4; ++r) {
            aI[r] = bf2f((u16)(xa.x >> (16 * r)));
            aF[r] = bf2f((u16)(xa.y >> (16 * r)));
        }
        {
            u64x2 xb = *(const u64x2*)(const void*)(xrow + xthr0 + 16);   // gates 2,3 nt0
#pragma unroll
            for (int r = 0; r < 4; ++r) {
                aG[r] = bf2f((u16)(xb.x >> (16 * r)));
                aO[r] = bf2f((u16)(xb.y >> (16 * r)));
            }
        }
        // issue phase-1 xg loads now (consumed after phase-0)
        u64x2 xc = *(const u64x2*)(const void*)(xrow + xthr1);
        u64x2 xd = *(const u64x2*)(const void*)(xrow + xthr1 + 16);

        const u16* hb = h_all[s & 1];
        u16* hw = h_all[(s & 1) ^ 1];
        u16* hsbase = hsd + ((size_t)(t * 32 + half * 16 + hrow)) * 256 + cbase;

#pragma unroll
        for (int kc = 0; kc < 8; ++kc) {
            short8 a = *(const short8*)(const void*)(hb + aoff + kc * 32);
            short8 b3 = ((const short8*)(const void*)wh3)[((wv * 2 + 0) * 8 + kc) * 64 + l];
            aI = __builtin_amdgcn_mfma_f32_16x16x32_bf16(a, whb[0][0][kc], aI, 0, 0, 0);
            aF = __builtin_amdgcn_mfma_f32_16x16x32_bf16(a, whb[1][0][kc], aF, 0, 0, 0);
            aG = __builtin_amdgcn_mfma_f32_16x16x32_bf16(a, whb[2][0][kc], aG, 0, 0, 0);
            aO = __builtin_amdgcn_mfma_f32_16x16x32_bf16(a, b3, aO, 0, 0, 0);
        }
#pragma unroll
        for (int r = 0; r < 4; ++r) {
            float ig = sigm(aI[r]), fg = sigm(aF[r]), gt = tanh_f(aG[r]), og = sigm(aO[r]);
            float cn = fg * cs0[r] + ig * gt;
            float hn = og * tanh_f(cn);
            int Lv = (int)(((r < 2) ? (Lp0 >> (16 * (r & 1))) : (Lp1 >> (16 * (r & 1)))) & 0xffffu);
            if (dir && t >= Lv) { cn = cs0[r]; hn = 0.0f; }
            cs0[r] = cn;
            u16 hbf = f2bf(hn);
            hw[(hrow + r) * 264 + cbase] = hbf;
            hsbase[(size_t)r * 256] = hbf;
        }

        // ---- phase 1 (cols cbase+16, nt=1): acc init from xc,xd ----
#pragma unroll
        for (int r = 0; r < 4; ++r) {
            aI[r] = bf2f((u16)(xc.x >> (16 * r)));
            aF[r] = bf2f((u16)(xc.y >> (16 * r)));
            aG[r] = bf2f((u16)(xd.x >> (16 * r)));
            aO[r] = bf2f((u16)(xd.y >> (16 * r)));
        }
        // prefetch NEXT step's nt0 gates 0,1 (hidden under phase-1 MFMA)
        {
            int sn = (s < 511) ? (s + 1) : s;
            int tn = dir ? (511 - sn) : sn;
            xa = *(const u64x2*)(const void*)(xgb + (size_t)tn * 65536 + xthr0);
        }
#pragma unroll
        for (int kc = 0; kc < 8; ++kc) {
            short8 a = *(const short8*)(const void*)(hb + aoff + kc * 32);
            short8 b3 = ((const short8*)(const void*)wh3)[((wv * 2 + 1) * 8 + kc) * 64 + l];
            aI = __builtin_amdgcn_mfma_f32_16x16x32_bf16(a, whb[0][1][kc], aI, 0, 0, 0);
            aF = __builtin_amdgcn_mfma_f32_16x16x32_bf16(a, whb[1][1][kc], aF, 0, 0, 0);
            aG = __builtin_amdgcn_mfma_f32_16x16x32_bf16(a, whb[2][1][kc], aG, 0, 0, 0);
            aO = __builtin_amdgcn_mfma_f32_16x16x32_bf16(a, b3, aO, 0, 0, 0);
        }
#pragma unroll
        for (int r = 0; r < 4; ++r) {
            float ig = sigm(aI[r]), fg = sigm(aF[r]), gt = tanh_f(aG[r]), og = sigm(aO[r]);
            float cn = fg * cs1[r] + ig * gt;
            float hn = og * tanh_f(cn);
            int Lv = (int)(((r < 2) ? (Lp0 >> (16 * (r & 1))) : (Lp1 >> (16 * (r & 1)))) & 0xffffu);
            if (dir && t >= Lv) { cn = cs1[r]; hn = 0.0f; }
            cs1[r] = cn;
            u16 hbf = f2bf(hn);
            hw[(hrow + r) * 264 + cbase + 16] = hbf;
            hsbase[(size_t)r * 256 + 16] = hbf;
        }

        // Barrier WITHOUT vmcnt drain: only LDS writes must be visible.
        asm volatile("s_waitcnt lgkmcnt(0)" ::: "memory");
        __builtin_amdgcn_sched_barrier(0);
        __builtin_amdgcn_s_barrier();
        __builtin_amdgcn_sched_barrier(0);
    }
}

// ---------------- K4: logits = log_softmax([hf;hb] @ out_W + out_b) ---------------
__global__ __launch_bounds__(256) void k4_proj(const u16* __restrict__ hs, const u16* __restrict__ outWb,
                                               const float* __restrict__ out_b, float* __restrict__ logits) {
    int r = blockIdx.x * 8 + (threadIdx.x >> 5);
    int n = threadIdx.x & 31;
    const u16* hf = hs + (size_t)r * 256;
    const u16* hbk = hs + 4194304ull + (size_t)r * 256;
    float acc = out_b[n];
#pragma unroll 4
    for (int k = 0; k < 256; k += 2) {
        u32 hv = *(const u32*)(const void*)(hf + k);
        acc += bf2f((u16)hv) * bf2f(outWb[k * 32 + n]);
        acc += bf2f((u16)(hv >> 16)) * bf2f(outWb[(k + 1) * 32 + n]);
    }
#pragma unroll 4
    for (int k = 0; k < 256; k += 2) {
        u32 hv = *(const u32*)(const void*)(hbk + k);
        acc += bf2f((u16)hv) * bf2f(outWb[(256 + k) * 32 + n]);
        acc += bf2f((u16)(hv >> 16)) * bf2f(outWb[(257 + k) * 32 + n]);
    }
    float m = acc;
#pragma unroll
    for (int d2 = 16; d2 >= 1; d2 >>= 1) m = fmaxf(m, __shfl_xor(m, d2, 32));
    float s = __expf(acc - m);
#pragma unroll
    for (int d2 = 16; d2 >= 1; d2 >>= 1) s += __shfl_xor(s, d2, 32);
    logits[(size_t)r * 32 + n] = acc - m - __logf(s);
}

// ---------------- K5: CRF forward + gold score -> out[b] --------------------------
__global__ __launch_bounds__(256) void k5_crf(const float* __restrict__ logits, const int* __restrict__ target,
                                              const int* __restrict__ seq_len, const float* __restrict__ trans,
                                              const float* __restrict__ start_trans, const float* __restrict__ end_trans,
                                              float* __restrict__ out) {
    int b = blockIdx.x;
    int tid = threadIdx.x;
    int L = seq_len[b];
    __shared__ float alpha[32];
    __shared__ float red[4];
    __shared__ float goldsh;

    // gold path score
    float part = 0.0f;
    for (int t = tid; t < 512; t += 256) {
        if (t < L) {
            int tg = target[b * 512 + t];
            part += logits[((size_t)(t * 32 + b)) * 32 + tg];
            if (t >= 1) part += trans[target[b * 512 + t - 1] * 32 + tg];
        }
    }
#pragma unroll
    for (int d2 = 32; d2 >= 1; d2 >>= 1) part += __shfl_xor(part, d2, 64);
    if ((tid & 63) == 0) red[tid >> 6] = part;
    __syncthreads();
    if (tid == 0) {
        float g = red[0] + red[1] + red[2] + red[3];
        g += start_trans[target[b * 512]];
        g += end_trans[target[b * 512 + L - 1]];
        goldsh = g;
    }
    if (tid < 32) alpha[tid] = logits[(size_t)b * 32 + tid] + start_trans[tid];
    __syncthreads();

    int j = tid >> 3, uu = tid & 7;
    float tr4[4];
#pragma unroll
    for (int r = 0; r < 4; ++r) tr4[r] = trans[(uu * 4 + r) * 32 + j];
    float e_next = logits[((size_t)(32 + b)) * 32 + j];
    for (int t = 1; t < 512; ++t) {
        float e = e_next;
        if (t < 511) e_next = logits[((size_t)((t + 1) * 32 + b)) * 32 + j];
        float a0 = alpha[uu * 4 + 0] + tr4[0];
        float a1 = alpha[uu * 4 + 1] + tr4[1];
        float a2 = alpha[uu * 4 + 2] + tr4[2];
        float a3 = alpha[uu * 4 + 3] + tr4[3];
        float m = fmaxf(fmaxf(a0, a1), fmaxf(a2, a3));
#pragma unroll
        for (int d2 = 4; d2 >= 1; d2 >>= 1) m = fmaxf(m, __shfl_xor(m, d2, 8));
        float ss = __expf(a0 - m) + __expf(a1 - m) + __expf(a2 - m) + __expf(a3 - m);
#pragma unroll
        for (int d2 = 4; d2 >= 1; d2 >>= 1) ss += __shfl_xor(ss, d2, 8);
        float nv = e + m + __logf(ss);
        __syncthreads();
        if (uu == 0 && t < L) alpha[j] = nv;
        __syncthreads();
    }
    if (tid < 32) {
        float v = alpha[tid] + end_trans[tid];
        float m = v;
#pragma unroll
        for (int d2 = 16; d2 >= 1; d2 >>= 1) m = fmaxf(m, __shfl_xor(m, d2, 32));
        float s2 = __expf(v - m);
#pragma unroll
        for (int d2 = 16; d2 >= 1; d2 >>= 1) s2 += __shfl_xor(s2, d2, 32);
        if (tid == 0) out[b] = m + __logf(s2) - goldsh;
    }
}

extern "C" void kernel_launch(void* const* d_in, const int* in_sizes, int n_in,
                              void* d_out, int out_size, void* d_ws, size_t ws_size,
                              hipStream_t stream) {
    if (ws_size < WS_NEED) return;  // workspace too small: fail cleanly, no OOB
    const int* chars = (const int*)d_in[0];
    const int* bigrams = (const int*)d_in[1];
    const int* seq_len = (const int*)d_in[2];
    const int* target = (const int*)d_in[3];
    const float* char_table = (const float*)d_in[4];
    const float* bigram_table = (const float*)d_in[5];
    const float* Wi_f = (const float*)d_in[6];
    const float* Wh_f = (const float*)d_in[7];
    const float* b_f = (const float*)d_in[8];
    const float* Wi_b = (const float*)d_in[9];
    const float* Wh_b = (const float*)d_in[10];
    const float* b_b = (const float*)d_in[11];
    const float* out_W = (const float*)d_in[12];
    const float* out_b = (const float*)d_in[13];
    const float* trans = (const float*)d_in[14];
    const float* start_trans = (const float*)d_in[15];
    const float* end_trans = (const float*)d_in[16];

    char* ws = (char*)d_ws;
    u16* emb = (u16*)(ws + O_EMB);
    u16* xg = (u16*)(ws + O_XG);
    u16* hs = (u16*)(ws + O_HS);
    float* logits = (float*)(ws + O_LOGITS);
    u16* WhT = (u16*)(ws + O_LOGITS);    // parked in logits region; dead before k4 writes logits
    u16* WiT = (u16*)(ws + O_WIT);
    u16* outWb = (u16*)(ws + O_OUTW);

    hipLaunchKernelGGL(k0_prep, dim3(4160), dim3(256), 0, stream, Wi_f, Wi_b, Wh_f, Wh_b, out_W, WiT, WhT, outWb);
    hipLaunchKernelGGL(k1_embed, dim3(8192), dim3(256), 0, stream, chars, bigrams, char_table, bigram_table, emb);
    hipLaunchKernelGGL(k2_gemm, dim3(256, 16, 2), dim3(256), 0, stream, emb, WiT, b_f, b_b, xg);
    hipLaunchKernelGGL(k3_lstm, dim3(4), dim3(512), 0, stream, xg, WhT, seq_len, hs);
    hipLaunchKernelGGL(k4_proj, dim3(2048), dim3(256), 0, stream, hs, outWb, out_b, logits);
    hipLaunchKernelGGL(k5_crf, dim3(32), dim3(256), 0, stream, logits, target, seq_len, trans, start_trans, end_trans,
                       (float*)d_out);
}